// Round 4
// baseline (1139.272 us; speedup 1.0000x reference)
//
#include <hip/hip_runtime.h>

// Problem constants (fixed by the reference)
#define T_SEQ   4096
#define BATCH   32
#define DIM     512
#define MROWS   (T_SEQ * BATCH)          // 131072 GEMM rows
#define S_STRIDE (BATCH * DIM)           // 16384 elements per time step
#define OUT_ELEMS ((size_t)T_SEQ * BATCH * DIM)   // 67108864
#define NCH     32                        // T-chunks for parallel scan
#define CLEN    (T_SEQ / NCH)             // 128 steps per chunk
#define NCHAIN  (BATCH * DIM)             // 16384 independent chains

// weight-stationary GEMM geometry
#define BROW    520                       // LDS row stride in shorts (512 + 8 pad)
#define LDS_BYTES (128 * BROW * 2)        // 133,120 B per block

typedef __bf16 bf8_t __attribute__((ext_vector_type(8)));    // 8 bf16 = 4 VGPRs
typedef float  f4_t  __attribute__((ext_vector_type(4)));
typedef unsigned short u16x8 __attribute__((ext_vector_type(8)));

__device__ __forceinline__ unsigned short f2bf(float f) {
    unsigned int u = __float_as_uint(f);
    u += 0x7FFFu + ((u >> 16) & 1u);     // round-to-nearest-even
    return (unsigned short)(u >> 16);
}
__device__ __forceinline__ float bf2f(unsigned short b) {
    return __uint_as_float(((unsigned int)b) << 16);
}

// ---------------- f32 -> bf16 convert (weights only) -----------------
__global__ __launch_bounds__(256) void k_cvt(const float* __restrict__ in,
                                             unsigned short* __restrict__ out) {
    size_t i = ((size_t)blockIdx.x * 256 + threadIdx.x) * 8;
    float4 a = *reinterpret_cast<const float4*>(in + i);
    float4 b = *reinterpret_cast<const float4*>(in + i + 4);
    u16x8 o;
    o[0] = f2bf(a.x); o[1] = f2bf(a.y); o[2] = f2bf(a.z); o[3] = f2bf(a.w);
    o[4] = f2bf(b.x); o[5] = f2bf(b.y); o[6] = f2bf(b.z); o[7] = f2bf(b.w);
    *reinterpret_cast<u16x8*>(out + i) = o;
}

// ---------------- weight-stationary bf16 GEMM ------------------------
// C[M,512] = A[M,512] * B[512,512]^T, B row-major [N][K].
// One block per (N-tile, M-group): 4 x 64 = 256 blocks = 1/CU.
// B-tile [128][512] staged in padded LDS ONCE; then 8 M-subtiles x 16 K-steps
// with NO barriers: each wave owns 32 private A-rows, A goes global->reg
// (2-step prefetch), B-frags from LDS (1-step prefetch, conflict-free pad).
// AF32=1: A is f32, converted to bf16 in registers (bit-identical f2bf).
template <int AF32>
__global__ __launch_bounds__(512, 2)
void k_gemm_rs(const void* __restrict__ Ap,
               const unsigned short* __restrict__ B,
               unsigned short* __restrict__ C) {
    extern __shared__ unsigned short Bs[];   // [128][BROW]

    const int tid  = threadIdx.x;
    const int lane = tid & 63;
    const int w    = tid >> 6;          // wave 0..7
    const int l15  = lane & 15;
    const int lk   = (lane >> 4) * 8;   // k-slot within BK=32
    const int n_t  = blockIdx.x >> 6;   // N-tile 0..3
    const int mg   = blockIdx.x & 63;   // M-group 0..63  (bx%8 == mg%8 -> XCD share)
    const int gn   = n_t * 128;

    // ---- stage B tile once: thread t -> col t/4, 16 segments of 16B ----
    {
        const int lc = tid >> 2, s0 = tid & 3;
        const unsigned short* gB = B + (size_t)(gn + lc) * 512;
#pragma unroll
        for (int j = 0; j < 16; ++j) {
            const int seg = j * 4 + s0;     // 0..63
            u16x8 v = *reinterpret_cast<const u16x8*>(gB + seg * 8);
            *reinterpret_cast<u16x8*>(&Bs[lc * BROW + seg * 8]) = v;
        }
    }
    __syncthreads();    // only barrier in the kernel

    const int bbase = l15 * BROW + lk;   // per-lane B read base (shorts)

    for (int ms = 0; ms < 8; ++ms) {
        const size_t R0 = (size_t)mg * 2048 + ms * 256 + w * 32;
        f4_t acc[2][8] = {};

        // per-lane A row pointers (rows R0+m*16+l15)
        const unsigned short* arp[2];
        const float*          afp[2];
#pragma unroll
        for (int m = 0; m < 2; ++m) {
            if constexpr (AF32) afp[m] = (const float*)Ap + (R0 + m * 16 + l15) * 512;
            else                arp[m] = (const unsigned short*)Ap + (R0 + m * 16 + l15) * 512;
        }

        bf8_t a0[2], a1[2], a2[2], b0[8], b1[8];

        // A-frag loader (k0 in shorts/floats)
#define LOAD_A(dst, k0)                                                        \
        _Pragma("unroll")                                                      \
        for (int m = 0; m < 2; ++m) {                                          \
            if constexpr (AF32) {                                              \
                float4 f0 = *reinterpret_cast<const float4*>(afp[m] + (k0) + lk);     \
                float4 f1 = *reinterpret_cast<const float4*>(afp[m] + (k0) + lk + 4); \
                u16x8 o;                                                       \
                o[0] = f2bf(f0.x); o[1] = f2bf(f0.y); o[2] = f2bf(f0.z); o[3] = f2bf(f0.w); \
                o[4] = f2bf(f1.x); o[5] = f2bf(f1.y); o[6] = f2bf(f1.z); o[7] = f2bf(f1.w); \
                dst[m] = *reinterpret_cast<bf8_t*>(&o);                        \
            } else {                                                           \
                dst[m] = *reinterpret_cast<const bf8_t*>(arp[m] + (k0) + lk);  \
            }                                                                  \
        }
#define LOAD_B(dst, k0)                                                        \
        _Pragma("unroll")                                                      \
        for (int n = 0; n < 8; ++n)                                            \
            dst[n] = *reinterpret_cast<const bf8_t*>(&Bs[bbase + n * 16 * BROW + (k0)]);

        // prologue: prefetch ks=0,1 (A two deep, B one deep)
        LOAD_A(a0, 0)
        LOAD_A(a1, 32)
        LOAD_B(b0, 0)

#pragma unroll
        for (int ks = 0; ks < 16; ++ks) {
            const int k0 = ks * 32;
            if (ks < 14) { LOAD_A(a2, k0 + 64) }
            if (ks < 15) { LOAD_B(b1, k0 + 32) }
#pragma unroll
            for (int m = 0; m < 2; ++m)
#pragma unroll
                for (int n = 0; n < 8; ++n)
                    acc[m][n] = __builtin_amdgcn_mfma_f32_16x16x32_bf16(a0[m], b0[n], acc[m][n], 0, 0, 0);
            // rotate pipeline (static copies)
#pragma unroll
            for (int m = 0; m < 2; ++m) { a0[m] = a1[m]; a1[m] = a2[m]; }
#pragma unroll
            for (int n = 0; n < 8; ++n) b0[n] = b1[n];
        }
#undef LOAD_A
#undef LOAD_B

        // epilogue: C/D layout col=lane&15, row=(lane>>4)*4+reg
        const int crow0 = (lane >> 4) * 4;
#pragma unroll
        for (int m = 0; m < 2; ++m)
#pragma unroll
            for (int n = 0; n < 8; ++n) {
                const size_t row0 = R0 + m * 16 + crow0;
                const int    col  = gn + n * 16 + l15;
#pragma unroll
                for (int r = 0; r < 4; ++r)
                    C[(row0 + r) * 512 + col] = f2bf(acc[m][n][r]);
            }
    }
}

// ------------- chunk-parallel scan, pass 1: per-chunk (A,B) summaries -------
__global__ __launch_bounds__(256)
void k_scan_p1(const unsigned short* __restrict__ q,
               const float* __restrict__ w_hh,
               const float* __restrict__ b_ih,
               float* __restrict__ Asum,
               float* __restrict__ Bsum) {
    const int g = (blockIdx.x & 63) * 256 + threadIdx.x;
    const int c = blockIdx.x >> 6;
    const float w  = w_hh[g & 511];
    const float bs = b_ih[g & 511];
    const unsigned short* p = q + (size_t)c * CLEN * S_STRIDE + g;

    float A = 0.f, Bv = 0.f;
    float s0[8], s1[8];
#pragma unroll
    for (int j = 0; j < 8; ++j) s0[j] = bf2f(p[(size_t)j * S_STRIDE]);
#pragma unroll
    for (int j = 0; j < 8; ++j) s1[j] = bf2f(p[(size_t)(8 + j) * S_STRIDE]);

    for (int j0 = 0; j0 < CLEN; j0 += 16) {
#pragma unroll
        for (int j = 0; j < 8; ++j) {
            float qv = s0[j] + bs;
            A  = fmaxf(fmaf(w, A, qv), 0.f);
            Bv = fmaf(w, Bv, qv);
        }
        if (j0 + 16 < CLEN) {
#pragma unroll
            for (int j = 0; j < 8; ++j) s0[j] = bf2f(p[(size_t)(j0 + 16 + j) * S_STRIDE]);
        }
#pragma unroll
        for (int j = 0; j < 8; ++j) {
            float qv = s1[j] + bs;
            A  = fmaxf(fmaf(w, A, qv), 0.f);
            Bv = fmaf(w, Bv, qv);
        }
        if (j0 + 24 < CLEN) {
#pragma unroll
            for (int j = 0; j < 8; ++j) s1[j] = bf2f(p[(size_t)(j0 + 24 + j) * S_STRIDE]);
        }
    }
    Asum[(size_t)c * NCHAIN + g] = A;
    Bsum[(size_t)c * NCHAIN + g] = Bv;
}

// ------------- pass 2: per-block stitch + exact replay ----------------------
template <int MODE>
__global__ __launch_bounds__(256)
void k_scan_p2(const unsigned short* __restrict__ q,
               const float* __restrict__ w_hh,
               const float* __restrict__ b_ih,
               const float* __restrict__ Asum,
               const float* __restrict__ Bsum,
               float* __restrict__ of32,
               unsigned short* __restrict__ ob16,
               float* __restrict__ hT) {
    const int g = (blockIdx.x & 63) * 256 + threadIdx.x;
    const int c = blockIdx.x >> 6;
    const float w  = w_hh[g & 511];
    const float bs = b_ih[g & 511];

    float cw = w;
#pragma unroll
    for (int i = 0; i < 7; ++i) cw *= cw;      // w^128
    float h = 0.f;
    for (int cc = 0; cc < c; ++cc)
        h = fmaxf(Asum[(size_t)cc * NCHAIN + g], fmaf(cw, h, Bsum[(size_t)cc * NCHAIN + g]));

    const size_t base = (size_t)c * CLEN * S_STRIDE + g;
    const unsigned short* p = q + base;

    float s0[8], s1[8];
#pragma unroll
    for (int j = 0; j < 8; ++j) s0[j] = bf2f(p[(size_t)j * S_STRIDE]);
#pragma unroll
    for (int j = 0; j < 8; ++j) s1[j] = bf2f(p[(size_t)(8 + j) * S_STRIDE]);

    for (int j0 = 0; j0 < CLEN; j0 += 16) {
#pragma unroll
        for (int j = 0; j < 8; ++j) {
            h = fmaxf(fmaf(w, h, s0[j] + bs), 0.f);
            const size_t idx = base + (size_t)(j0 + j) * S_STRIDE;
            if (MODE == 0) of32[idx] = h; else ob16[idx] = f2bf(h);
        }
        if (j0 + 16 < CLEN) {
#pragma unroll
            for (int j = 0; j < 8; ++j) s0[j] = bf2f(p[(size_t)(j0 + 16 + j) * S_STRIDE]);
        }
#pragma unroll
        for (int j = 0; j < 8; ++j) {
            h = fmaxf(fmaf(w, h, s1[j] + bs), 0.f);
            const size_t idx = base + (size_t)(j0 + 8 + j) * S_STRIDE;
            if (MODE == 0) of32[idx] = h; else ob16[idx] = f2bf(h);
        }
        if (j0 + 24 < CLEN) {
#pragma unroll
            for (int j = 0; j < 8; ++j) s1[j] = bf2f(p[(size_t)(j0 + 24 + j) * S_STRIDE]);
        }
    }
    if (c == NCH - 1) hT[g] = h;
}

extern "C" void kernel_launch(void* const* d_in, const int* in_sizes, int n_in,
                              void* d_out, int out_size, void* d_ws, size_t ws_size,
                              hipStream_t stream) {
    const float* x    = (const float*)d_in[0];   // (4096,32,512)
    const float* W_ih = (const float*)d_in[1];   // (2,512,512)
    const float* w_hh = (const float*)d_in[2];   // (2,512)
    const float* b_ih = (const float*)d_in[3];   // (2,512)

    // ---- workspace layout (~139 MB) ----
    unsigned short* proj2 = (unsigned short*)d_ws;                // 134 MB
    unsigned short* Wb    = proj2 + OUT_ELEMS;                    // 1 MB
    float* Asum = (float*)(Wb + 2 * 512 * 512);                   // 2 MB
    float* Bsum = Asum + (size_t)NCH * NCHAIN;                    // 2 MB

    // ---- d_out staging: proj1 (bf16) lower half, ys1 (bf16) upper half ----
    unsigned short* proj1 = (unsigned short*)d_out;
    unsigned short* ys1   = proj1 + OUT_ELEMS;
    float* out = (float*)d_out;
    float* hT  = out + OUT_ELEMS;                                 // h_n (2,32,512)

    const int sgrid = 64 * NCH;             // 2048 blocks for scan passes

    // 1. W -> bf16
    k_cvt<<<524288 / 8 / 256, 256, 0, stream>>>(W_ih, Wb);
    // 2. layer-0 GEMM (A = x f32, fused cvt) -> proj1
    k_gemm_rs<1><<<256, 512, LDS_BYTES, stream>>>(x, Wb, proj1);
    // 3-4. layer-0 chunked scan -> ys1 (bf16) + hT0
    k_scan_p1<<<sgrid, 256, 0, stream>>>(proj1, w_hh, b_ih, Asum, Bsum);
    k_scan_p2<1><<<sgrid, 256, 0, stream>>>(proj1, w_hh, b_ih, Asum, Bsum,
                                            nullptr, ys1, hT);
    // 5. layer-1 GEMM (A = ys1 bf16) -> proj2 (ws)
    k_gemm_rs<0><<<256, 512, LDS_BYTES, stream>>>(ys1, Wb + 512 * 512, proj2);
    // 6-7. layer-1 chunked scan -> final out (f32, overwrites proj1/ys1) + hT1
    k_scan_p1<<<sgrid, 256, 0, stream>>>(proj2, w_hh + DIM, b_ih + DIM, Asum, Bsum);
    k_scan_p2<0><<<sgrid, 256, 0, stream>>>(proj2, w_hh + DIM, b_ih + DIM, Asum, Bsum,
                                            out, nullptr, hT + NCHAIN);
}

// Round 5
// 465.840 us; speedup vs baseline: 2.4456x; 2.4456x over previous
//
#include <hip/hip_runtime.h>

// Problem constants (fixed by the reference)
#define T_SEQ   4096
#define BATCH   32
#define DIM     512
#define MROWS   (T_SEQ * BATCH)          // 131072 GEMM rows
#define S_STRIDE (BATCH * DIM)           // 16384 elements per time step
#define OUT_ELEMS ((size_t)T_SEQ * BATCH * DIM)   // 67108864
#define NCH     32                        // T-chunks for parallel scan
#define CLEN    (T_SEQ / NCH)             // 128 steps per chunk
#define NCHAIN  (BATCH * DIM)             // 16384 independent chains
#define NWG     ((MROWS / 128) * (DIM / 128))     // 4096 GEMM workgroups

typedef __bf16 bf8_t __attribute__((ext_vector_type(8)));    // 8 bf16 = 4 VGPRs
typedef float  f4_t  __attribute__((ext_vector_type(4)));
typedef unsigned short u16x8 __attribute__((ext_vector_type(8)));
typedef __attribute__((address_space(1))) void gvoid_t;
typedef __attribute__((address_space(3))) void lvoid_t;

__device__ __forceinline__ unsigned short f2bf(float f) {
    unsigned int u = __float_as_uint(f);
    u += 0x7FFFu + ((u >> 16) & 1u);     // round-to-nearest-even
    return (unsigned short)(u >> 16);
}
__device__ __forceinline__ float bf2f(unsigned short b) {
    return __uint_as_float(((unsigned int)b) << 16);
}

// ---------------- f32 -> bf16 convert (weights only) -----------------
__global__ __launch_bounds__(256) void k_cvt(const float* __restrict__ in,
                                             unsigned short* __restrict__ out) {
    size_t i = ((size_t)blockIdx.x * 256 + threadIdx.x) * 8;
    float4 a = *reinterpret_cast<const float4*>(in + i);
    float4 b = *reinterpret_cast<const float4*>(in + i + 4);
    u16x8 o;
    o[0] = f2bf(a.x); o[1] = f2bf(a.y); o[2] = f2bf(a.z); o[3] = f2bf(a.w);
    o[4] = f2bf(b.x); o[5] = f2bf(b.y); o[6] = f2bf(b.z); o[7] = f2bf(b.w);
    *reinterpret_cast<u16x8*>(out + i) = o;
}

// ---------------- bf16 GEMM  C[M,512] = A[M,512] * B[512,512]^T ------
// 128x128 tile, BK=32, 4 waves, DOUBLE-BUFFERED LDS (2-phase pipeline):
// per K-step issue next-tile staging FIRST, then ds_read+MFMA current tile,
// one __syncthreads per step (drains vmcnt+lgkmcnt).
// AF32=1: A f32 -> regs early (T14 async-split), cvt+ds_write AFTER compute.
// XCD swizzle: the 4 N-tiles of an M-tile are consecutive -> same XCD L2.
template <int AF32>
__global__ __launch_bounds__(256)
void k_gemm_bt(const void* __restrict__ Ap,
               const unsigned short* __restrict__ B,
               unsigned short* __restrict__ C) {
    __shared__ unsigned short As[2][128 * 32];
    __shared__ unsigned short Bs[2][128 * 32];

    const int tid  = threadIdx.x;
    const int lane = tid & 63;
    const int wv   = tid >> 6;
    const int wr   = wv >> 1;
    const int wc   = wv & 1;

    // bijective XCD swizzle (NWG % 8 == 0)
    const int flat = blockIdx.x;
    const int s    = (flat & 7) * (NWG / 8) + (flat >> 3);
    const size_t gm = (size_t)(s >> 2) * 128;   // M-tile (1024)
    const int    gn = (s & 3) * 128;            // N-tile (4)

    const int srow = tid >> 2;          // 0..63
    const int skk  = (tid & 3) * 8;     // 0,8,16,24 (elements)

    f4_t acc[4][4] = {};
    const int l15 = lane & 15;
    const int lk  = (lane >> 4) * 8;

    float4 fa0[2], fa1[2];              // in-flight A f32 (AF32 path)

#define ISSUE_A_F32(k0)                                                        \
    _Pragma("unroll")                                                          \
    for (int i = 0; i < 2; ++i) {                                              \
        const float* ga = (const float*)Ap + (gm + (size_t)(i * 64 + srow)) * 512 + (k0) + skk; \
        fa0[i] = *reinterpret_cast<const float4*>(ga);                         \
        fa1[i] = *reinterpret_cast<const float4*>(ga + 4);                     \
    }
#define WRITE_A_F32(b)                                                         \
    _Pragma("unroll")                                                          \
    for (int i = 0; i < 2; ++i) {                                              \
        u16x8 o;                                                               \
        o[0] = f2bf(fa0[i].x); o[1] = f2bf(fa0[i].y); o[2] = f2bf(fa0[i].z); o[3] = f2bf(fa0[i].w); \
        o[4] = f2bf(fa1[i].x); o[5] = f2bf(fa1[i].y); o[6] = f2bf(fa1[i].z); o[7] = f2bf(fa1[i].w); \
        *reinterpret_cast<u16x8*>(&As[b][i * 2048 + tid * 8]) = o;             \
    }
#define GLL_A(b, k0)                                                           \
    _Pragma("unroll")                                                          \
    for (int i = 0; i < 2; ++i) {                                              \
        const unsigned short* ga = (const unsigned short*)Ap + (gm + (size_t)(i * 64 + srow)) * 512 + (k0) + skk; \
        __builtin_amdgcn_global_load_lds((gvoid_t*)ga, (lvoid_t*)&As[b][i * 2048 + wv * 512], 16, 0, 0); \
    }
#define GLL_B(b, k0)                                                           \
    _Pragma("unroll")                                                          \
    for (int i = 0; i < 2; ++i) {                                              \
        const unsigned short* gb = B + (size_t)(gn + i * 64 + srow) * 512 + (k0) + skk; \
        __builtin_amdgcn_global_load_lds((gvoid_t*)gb, (lvoid_t*)&Bs[b][i * 2048 + wv * 512], 16, 0, 0); \
    }

    // ---- prologue: stage tile 0 into buffer 0 ----
    if constexpr (AF32) { ISSUE_A_F32(0) } else { GLL_A(0, 0) }
    GLL_B(0, 0)
    if constexpr (AF32) { WRITE_A_F32(0) }
    __syncthreads();

#pragma unroll 2
    for (int ks = 0; ks < 16; ++ks) {
        const int cur = ks & 1;
        const int nxt = cur ^ 1;
        const int k1  = (ks + 1) * 32;

        // 1. issue next-tile staging (overlaps with compute below)
        if (ks < 15) {
            if constexpr (AF32) { ISSUE_A_F32(k1) } else { GLL_A(nxt, k1) }
            GLL_B(nxt, k1)
        }

        // 2. compute current tile from LDS
        bf8_t af[4], bfz[4];
#pragma unroll
        for (int m = 0; m < 4; ++m)
            af[m] = *reinterpret_cast<const bf8_t*>(&As[cur][(wr * 64 + m * 16 + l15) * 32 + lk]);
#pragma unroll
        for (int n = 0; n < 4; ++n)
            bfz[n] = *reinterpret_cast<const bf8_t*>(&Bs[cur][(wc * 64 + n * 16 + l15) * 32 + lk]);
#pragma unroll
        for (int m = 0; m < 4; ++m)
#pragma unroll
            for (int n = 0; n < 4; ++n)
                acc[m][n] = __builtin_amdgcn_mfma_f32_16x16x32_bf16(af[m], bfz[n], acc[m][n], 0, 0, 0);

        // 3. A cvt+LDS-write after compute (f32 loads have landed by now)
        if (ks < 15) {
            if constexpr (AF32) { WRITE_A_F32(nxt) }
        }
        __syncthreads();
    }
#undef ISSUE_A_F32
#undef WRITE_A_F32
#undef GLL_A
#undef GLL_B

    // C/D layout (HW-verified): col = lane&15, row = (lane>>4)*4 + reg
    const int crow0 = (lane >> 4) * 4;
#pragma unroll
    for (int m = 0; m < 4; ++m)
#pragma unroll
        for (int n = 0; n < 4; ++n) {
            const size_t row0 = gm + (size_t)(wr * 64 + m * 16 + crow0);
            const int    col  = gn + wc * 64 + n * 16 + l15;
#pragma unroll
            for (int r = 0; r < 4; ++r)
                C[(row0 + r) * 512 + col] = f2bf(acc[m][n][r]);
        }
}

// ------------- chunk-parallel scan, pass 1: per-chunk (A,B) summaries -------
__global__ __launch_bounds__(256)
void k_scan_p1(const unsigned short* __restrict__ q,
               const float* __restrict__ w_hh,
               const float* __restrict__ b_ih,
               float* __restrict__ Asum,
               float* __restrict__ Bsum) {
    const int g = (blockIdx.x & 63) * 256 + threadIdx.x;
    const int c = blockIdx.x >> 6;
    const float w  = w_hh[g & 511];
    const float bs = b_ih[g & 511];
    const unsigned short* p = q + (size_t)c * CLEN * S_STRIDE + g;

    float A = 0.f, Bv = 0.f;
    float s0[8], s1[8];
#pragma unroll
    for (int j = 0; j < 8; ++j) s0[j] = bf2f(p[(size_t)j * S_STRIDE]);
#pragma unroll
    for (int j = 0; j < 8; ++j) s1[j] = bf2f(p[(size_t)(8 + j) * S_STRIDE]);

    for (int j0 = 0; j0 < CLEN; j0 += 16) {
#pragma unroll
        for (int j = 0; j < 8; ++j) {
            float qv = s0[j] + bs;
            A  = fmaxf(fmaf(w, A, qv), 0.f);
            Bv = fmaf(w, Bv, qv);
        }
        if (j0 + 16 < CLEN) {
#pragma unroll
            for (int j = 0; j < 8; ++j) s0[j] = bf2f(p[(size_t)(j0 + 16 + j) * S_STRIDE]);
        }
#pragma unroll
        for (int j = 0; j < 8; ++j) {
            float qv = s1[j] + bs;
            A  = fmaxf(fmaf(w, A, qv), 0.f);
            Bv = fmaf(w, Bv, qv);
        }
        if (j0 + 24 < CLEN) {
#pragma unroll
            for (int j = 0; j < 8; ++j) s1[j] = bf2f(p[(size_t)(j0 + 24 + j) * S_STRIDE]);
        }
    }
    Asum[(size_t)c * NCHAIN + g] = A;
    Bsum[(size_t)c * NCHAIN + g] = Bv;
}

// ------------- pass 2: per-block stitch + exact replay ----------------------
template <int MODE>
__global__ __launch_bounds__(256)
void k_scan_p2(const unsigned short* __restrict__ q,
               const float* __restrict__ w_hh,
               const float* __restrict__ b_ih,
               const float* __restrict__ Asum,
               const float* __restrict__ Bsum,
               float* __restrict__ of32,
               unsigned short* __restrict__ ob16,
               float* __restrict__ hT) {
    const int g = (blockIdx.x & 63) * 256 + threadIdx.x;
    const int c = blockIdx.x >> 6;
    const float w  = w_hh[g & 511];
    const float bs = b_ih[g & 511];

    float cw = w;
#pragma unroll
    for (int i = 0; i < 7; ++i) cw *= cw;      // w^128
    float h = 0.f;
    for (int cc = 0; cc < c; ++cc)
        h = fmaxf(Asum[(size_t)cc * NCHAIN + g], fmaf(cw, h, Bsum[(size_t)cc * NCHAIN + g]));

    const size_t base = (size_t)c * CLEN * S_STRIDE + g;
    const unsigned short* p = q + base;

    float s0[8], s1[8];
#pragma unroll
    for (int j = 0; j < 8; ++j) s0[j] = bf2f(p[(size_t)j * S_STRIDE]);
#pragma unroll
    for (int j = 0; j < 8; ++j) s1[j] = bf2f(p[(size_t)(8 + j) * S_STRIDE]);

    for (int j0 = 0; j0 < CLEN; j0 += 16) {
#pragma unroll
        for (int j = 0; j < 8; ++j) {
            h = fmaxf(fmaf(w, h, s0[j] + bs), 0.f);
            const size_t idx = base + (size_t)(j0 + j) * S_STRIDE;
            if (MODE == 0) of32[idx] = h; else ob16[idx] = f2bf(h);
        }
        if (j0 + 16 < CLEN) {
#pragma unroll
            for (int j = 0; j < 8; ++j) s0[j] = bf2f(p[(size_t)(j0 + 16 + j) * S_STRIDE]);
        }
#pragma unroll
        for (int j = 0; j < 8; ++j) {
            h = fmaxf(fmaf(w, h, s1[j] + bs), 0.f);
            const size_t idx = base + (size_t)(j0 + 8 + j) * S_STRIDE;
            if (MODE == 0) of32[idx] = h; else ob16[idx] = f2bf(h);
        }
        if (j0 + 24 < CLEN) {
#pragma unroll
            for (int j = 0; j < 8; ++j) s1[j] = bf2f(p[(size_t)(j0 + 24 + j) * S_STRIDE]);
        }
    }
    if (c == NCH - 1) hT[g] = h;
}

extern "C" void kernel_launch(void* const* d_in, const int* in_sizes, int n_in,
                              void* d_out, int out_size, void* d_ws, size_t ws_size,
                              hipStream_t stream) {
    const float* x    = (const float*)d_in[0];   // (4096,32,512)
    const float* W_ih = (const float*)d_in[1];   // (2,512,512)
    const float* w_hh = (const float*)d_in[2];   // (2,512)
    const float* b_ih = (const float*)d_in[3];   // (2,512)

    // ---- workspace layout (~139 MB) ----
    unsigned short* proj2 = (unsigned short*)d_ws;                // 134 MB
    unsigned short* Wb    = proj2 + OUT_ELEMS;                    // 1 MB
    float* Asum = (float*)(Wb + 2 * 512 * 512);                   // 2 MB
    float* Bsum = Asum + (size_t)NCH * NCHAIN;                    // 2 MB

    // ---- d_out staging: proj1 (bf16) lower half, ys1 (bf16) upper half ----
    unsigned short* proj1 = (unsigned short*)d_out;
    unsigned short* ys1   = proj1 + OUT_ELEMS;
    float* out = (float*)d_out;
    float* hT  = out + OUT_ELEMS;                                 // h_n (2,32,512)

    const int sgrid = 64 * NCH;             // 2048 blocks for scan passes

    // 1. W -> bf16
    k_cvt<<<524288 / 8 / 256, 256, 0, stream>>>(W_ih, Wb);
    // 2. layer-0 GEMM (A = x f32, fused cvt) -> proj1
    k_gemm_bt<1><<<NWG, 256, 0, stream>>>(x, Wb, proj1);
    // 3-4. layer-0 chunked scan -> ys1 (bf16) + hT0
    k_scan_p1<<<sgrid, 256, 0, stream>>>(proj1, w_hh, b_ih, Asum, Bsum);
    k_scan_p2<1><<<sgrid, 256, 0, stream>>>(proj1, w_hh, b_ih, Asum, Bsum,
                                            nullptr, ys1, hT);
    // 5. layer-1 GEMM (A = ys1 bf16) -> proj2 (ws)
    k_gemm_bt<0><<<NWG, 256, 0, stream>>>(ys1, Wb + 512 * 512, proj2);
    // 6-7. layer-1 chunked scan -> final out (f32, overwrites proj1/ys1) + hT1
    k_scan_p1<<<sgrid, 256, 0, stream>>>(proj2, w_hh + DIM, b_ih + DIM, Asum, Bsum);
    k_scan_p2<0><<<sgrid, 256, 0, stream>>>(proj2, w_hh + DIM, b_ih + DIM, Asum, Bsum,
                                            out, nullptr, hT + NCHAIN);
}

// Round 6
// 408.231 us; speedup vs baseline: 2.7908x; 1.1411x over previous
//
#include <hip/hip_runtime.h>

// Problem constants (fixed by the reference)
#define T_SEQ   4096
#define BATCH   32
#define DIM     512
#define MROWS   (T_SEQ * BATCH)          // 131072 GEMM rows
#define S_STRIDE (BATCH * DIM)           // 16384 elements per time step
#define OUT_ELEMS ((size_t)T_SEQ * BATCH * DIM)   // 67108864
#define NCH     32                        // T-chunks for parallel scan
#define CLEN    (T_SEQ / NCH)             // 128 steps per chunk
#define NCHAIN  (BATCH * DIM)             // 16384 independent chains

// 8-phase GEMM geometry: BM=BN=256, BK=64, 8 waves (2Mx4N), LDS 128 KB
#define GNWG    ((MROWS / 256) * (DIM / 256))   // 1024 blocks
#define OFF_A0  0          // shorts; each region 16384 shorts = 32 KB
#define OFF_A1  16384
#define OFF_B0  32768
#define OFF_B1  49152
#define GLDS_B  131072

typedef __bf16 bf8_t __attribute__((ext_vector_type(8)));
typedef float  f4_t  __attribute__((ext_vector_type(4)));
typedef unsigned short u16x8 __attribute__((ext_vector_type(8)));
typedef __attribute__((address_space(1))) void gvoid_t;
typedef __attribute__((address_space(3))) void lvoid_t;

__device__ __forceinline__ unsigned short f2bf(float f) {
    unsigned int u = __float_as_uint(f);
    u += 0x7FFFu + ((u >> 16) & 1u);     // round-to-nearest-even
    return (unsigned short)(u >> 16);
}
__device__ __forceinline__ float bf2f(unsigned short b) {
    return __uint_as_float(((unsigned int)b) << 16);
}

#define VMC(n)  asm volatile("s_waitcnt vmcnt(" #n ")" ::: "memory")
#define LGKM0   asm volatile("s_waitcnt lgkmcnt(0)" ::: "memory")
#define PH_PRE()  do { __builtin_amdgcn_s_barrier(); LGKM0;                    \
                       __builtin_amdgcn_sched_barrier(0);                      \
                       __builtin_amdgcn_s_setprio(1); } while (0)
#define PH_POST() do { __builtin_amdgcn_s_setprio(0);                          \
                       __builtin_amdgcn_sched_barrier(0);                      \
                       __builtin_amdgcn_s_barrier(); } while (0)

// ---------------- f32 -> bf16 convert (weights only) -----------------
__global__ __launch_bounds__(256) void k_cvt(const float* __restrict__ in,
                                             unsigned short* __restrict__ out) {
    size_t i = ((size_t)blockIdx.x * 256 + threadIdx.x) * 8;
    float4 a = *reinterpret_cast<const float4*>(in + i);
    float4 b = *reinterpret_cast<const float4*>(in + i + 4);
    u16x8 o;
    o[0] = f2bf(a.x); o[1] = f2bf(a.y); o[2] = f2bf(a.z); o[3] = f2bf(a.w);
    o[4] = f2bf(b.x); o[5] = f2bf(b.y); o[6] = f2bf(b.z); o[7] = f2bf(b.w);
    *reinterpret_cast<u16x8*>(out + i) = o;
}

// ---------------- 8-phase 256x256 bf16 GEMM  C = A * B^T -------------
// K=512 -> 8 K-tiles (BK=64), 4 iterations x 8 phases, 2 LDS buffers.
// XOR swizzle: 16B slot s of row r stored at s^(r&7)  (T2; 2-way max).
// gll sources pre-inverse-swizzled (rule #21). vmcnt(4) at p3/p7 only (T4).
// AF32=1: A f32; loads issued in the A-stage slots, cvt+swizzled ds_write
// after that phase's MFMA (T14), drained by the same vmcnt points.
template <int AF32>
__global__ __launch_bounds__(512, 2)
void k_gemm8(const void* __restrict__ Ap,
             const unsigned short* __restrict__ Bp,
             unsigned short* __restrict__ C) {
    extern __shared__ unsigned short lds[];    // 65536 shorts = 128 KB

    const int tid  = threadIdx.x;
    const int lane = tid & 63;
    const int wv   = tid >> 6;          // wave 0..7
    const int wr   = wv >> 2;           // 0..1 -> M offset wr*128
    const int wc   = wv & 3;            // 0..3 -> N offset wc*64
    const int l15  = lane & 15;
    const int l16  = lane >> 4;
    const int lj   = lane >> 3;         // staging row-within-8
    const int ss8  = lane & 7;          // staging 16B-slot

    // bijective XCD swizzle (GNWG % 8 == 0); s,s^1 share the A-panel
    const int sid = (blockIdx.x & 7) * (GNWG / 8) + (blockIdx.x >> 3);
    const size_t gm = (size_t)(sid >> 1) * 256;
    const int    gn = (sid & 1) * 256;

    const unsigned short* Ab = (const unsigned short*)Ap;
    const float*          Af = (const float*)Ap;

    // ---- gll stage of one half-tile (bf16 source), inverse-swizzled src ----
    auto stage = [&](const unsigned short* gbase, size_t grow0, int region,
                     int half, int kt) {
#pragma unroll
        for (int j = 0; j < 2; ++j) {
            const int r = half * 128 + j * 64 + wv * 8 + lj;
            const unsigned short* src =
                gbase + (grow0 + r) * 512 + kt * 64 + ((ss8 ^ (r & 7)) * 8);
            unsigned short* dst = &lds[region + half * 8192 + j * 4096 + wv * 512];
            __builtin_amdgcn_global_load_lds((gvoid_t*)src, (lvoid_t*)dst, 16, 0, 0);
        }
    };
    // ---- f32-A reg staging: issue loads / cvt+swizzled ds_write ----
    auto loadAf = [&](float4* h, int half, int kt) {
#pragma unroll
        for (int j = 0; j < 2; ++j) {
            const int r = half * 128 + j * 64 + wv * 8 + lj;
            const float* src = Af + (gm + r) * 512 + kt * 64 + ss8 * 8;
            h[j * 2]     = *reinterpret_cast<const float4*>(src);
            h[j * 2 + 1] = *reinterpret_cast<const float4*>(src + 4);
        }
    };
    auto writeAf = [&](const float4* h, int region, int half) {
#pragma unroll
        for (int j = 0; j < 2; ++j) {
            const int r = half * 128 + j * 64 + wv * 8 + lj;
            float4 f0 = h[j * 2], f1 = h[j * 2 + 1];
            u16x8 o;
            o[0] = f2bf(f0.x); o[1] = f2bf(f0.y); o[2] = f2bf(f0.z); o[3] = f2bf(f0.w);
            o[4] = f2bf(f1.x); o[5] = f2bf(f1.y); o[6] = f2bf(f1.z); o[7] = f2bf(f1.w);
            *reinterpret_cast<u16x8*>(&lds[region + r * 64 + (ss8 ^ (r & 7)) * 8]) = o;
        }
    };

    f4_t  acc[8][4] = {};
    bf8_t bb[4][2];              // B frags of current K-tile
    bf8_t aq[2][2];              // A frags of current quadrant
    float4 afh0[4], afh1[4];     // in-flight f32 A halves (AF32)

    auto loadBall = [&](int region) {
#pragma unroll
        for (int n = 0; n < 4; ++n)
#pragma unroll
            for (int ks = 0; ks < 2; ++ks) {
                const int c  = wc * 64 + n * 16 + l15;
                const int sl = (ks * 4 + l16) ^ (l15 & 7);
                bb[n][ks] = *reinterpret_cast<const bf8_t*>(
                    (const char*)&lds[region] + c * 128 + sl * 16);
            }
    };
    auto loadAq = [&](int region, int q) {
#pragma unroll
        for (int m = 0; m < 2; ++m)
#pragma unroll
            for (int ks = 0; ks < 2; ++ks) {
                const int r  = wr * 128 + (q * 2 + m) * 16 + l15;
                const int sl = (ks * 4 + l16) ^ (l15 & 7);
                aq[m][ks] = *reinterpret_cast<const bf8_t*>(
                    (const char*)&lds[region] + r * 128 + sl * 16);
            }
    };
#define MFMA_Q(q)                                                              \
    _Pragma("unroll")                                                          \
    for (int m = 0; m < 2; ++m)                                                \
        _Pragma("unroll")                                                      \
        for (int n = 0; n < 4; ++n)                                            \
            _Pragma("unroll")                                                  \
            for (int ks = 0; ks < 2; ++ks)                                     \
                acc[(q) * 2 + m][n] = __builtin_amdgcn_mfma_f32_16x16x32_bf16( \
                    aq[m][ks], bb[n][ks], acc[(q) * 2 + m][n], 0, 0, 0);

    // ================= prologue: tile0 A+B, tile1 B =================
    if constexpr (AF32) {
        loadAf(afh0, 0, 0); loadAf(afh1, 1, 0);          // 8 loads
        stage(Bp, (size_t)gn, OFF_B0, 0, 0); stage(Bp, (size_t)gn, OFF_B0, 1, 0);
        stage(Bp, (size_t)gn, OFF_B1, 0, 1); stage(Bp, (size_t)gn, OFF_B1, 1, 1);
        VMC(8);                                           // A f32 landed
        writeAf(afh0, OFF_A0, 0); writeAf(afh1, OFF_A0, 1);
        VMC(4);                                           // B0 landed, B1 in flight
        LGKM0;
    } else {
        stage(Ab, gm, OFF_A0, 0, 0); stage(Ab, gm, OFF_A0, 1, 0);
        stage(Bp, (size_t)gn, OFF_B0, 0, 0); stage(Bp, (size_t)gn, OFF_B0, 1, 0);
        stage(Bp, (size_t)gn, OFF_B1, 0, 1); stage(Bp, (size_t)gn, OFF_B1, 1, 1);
        VMC(4);
    }
    __builtin_amdgcn_s_barrier();

    // ================= main loop: 4 iters x 8 phases =================
#pragma unroll
    for (int i = 0; i < 4; ++i) {
        const int t1 = 2 * i + 1, t2 = 2 * i + 2, t3 = 2 * i + 3;
        const bool st2 = (i < 3);      // stage tiles t2/t3 only while they exist

        // ---- p0: Btile read + A-quad0 of tile 2i; stage A1h0(t1) ----
        loadBall(OFF_B0); loadAq(OFF_A0, 0);
        if constexpr (AF32) { loadAf(afh0, 0, t1); } else { stage(Ab, gm, OFF_A1, 0, t1); }
        PH_PRE(); MFMA_Q(0); PH_POST();
        // ---- p1: quad1; stage A1h1(t1) ----
        loadAq(OFF_A0, 1);
        if constexpr (AF32) { loadAf(afh1, 1, t1); } else { stage(Ab, gm, OFF_A1, 1, t1); }
        PH_PRE(); MFMA_Q(1); PH_POST();
        // ---- p2: quad2; stage B0h0(t2); AF32: retire A1h0 ----
        loadAq(OFF_A0, 2);
        if (st2) stage(Bp, (size_t)gn, OFF_B0, 0, t2);
        PH_PRE(); MFMA_Q(2);
        __builtin_amdgcn_s_setprio(0); __builtin_amdgcn_sched_barrier(0);
        if constexpr (AF32) {
            if (st2) { VMC(6); } else { VMC(4); }
            writeAf(afh0, OFF_A1, 0);
        }
        __builtin_amdgcn_s_barrier();
        // ---- p3: quad3; stage B0h1(t2); vmcnt; AF32: retire A1h1 ----
        loadAq(OFF_A0, 3);
        if (st2) stage(Bp, (size_t)gn, OFF_B0, 1, t2);
        PH_PRE(); MFMA_Q(3);
        __builtin_amdgcn_s_setprio(0); __builtin_amdgcn_sched_barrier(0);
        if constexpr (AF32) {
            if (st2) { VMC(4); } else { VMC(0); }
            writeAf(afh1, OFF_A1, 1);
            LGKM0;
        } else {
            if (st2) { VMC(4); } else { VMC(0); }
        }
        __builtin_amdgcn_s_barrier();

        // ---- p4: Btile read + quad0 of tile 2i+1; stage A0h0(t2) ----
        loadBall(OFF_B1); loadAq(OFF_A1, 0);
        if (st2) { if constexpr (AF32) { loadAf(afh0, 0, t2); } else { stage(Ab, gm, OFF_A0, 0, t2); } }
        PH_PRE(); MFMA_Q(0); PH_POST();
        // ---- p5: quad1; stage A0h1(t2) ----
        loadAq(OFF_A1, 1);
        if (st2) { if constexpr (AF32) { loadAf(afh1, 1, t2); } else { stage(Ab, gm, OFF_A0, 1, t2); } }
        PH_PRE(); MFMA_Q(1); PH_POST();
        // ---- p6: quad2; stage B1h0(t3); AF32: retire A0h0 ----
        loadAq(OFF_A1, 2);
        if (st2) stage(Bp, (size_t)gn, OFF_B1, 0, t3);
        PH_PRE(); MFMA_Q(2);
        __builtin_amdgcn_s_setprio(0); __builtin_amdgcn_sched_barrier(0);
        if constexpr (AF32) { if (st2) { VMC(6); writeAf(afh0, OFF_A0, 0); } }
        __builtin_amdgcn_s_barrier();
        // ---- p7: quad3; stage B1h1(t3); vmcnt; AF32: retire A0h1 ----
        loadAq(OFF_A1, 3);
        if (st2) stage(Bp, (size_t)gn, OFF_B1, 1, t3);
        PH_PRE(); MFMA_Q(3);
        __builtin_amdgcn_s_setprio(0); __builtin_amdgcn_sched_barrier(0);
        if (st2) {
            VMC(4);
            if constexpr (AF32) { writeAf(afh1, OFF_A0, 1); LGKM0; }
        }
        __builtin_amdgcn_s_barrier();
    }
#undef MFMA_Q

    // ================= epilogue: C/D col=lane&15, row=(lane>>4)*4+reg ====
    const int crow0 = l16 * 4;
#pragma unroll
    for (int m = 0; m < 8; ++m)
#pragma unroll
        for (int n = 0; n < 4; ++n) {
            const size_t row0 = gm + (size_t)(wr * 128 + m * 16 + crow0);
            const int    col  = gn + wc * 64 + n * 16 + l15;
#pragma unroll
            for (int r = 0; r < 4; ++r)
                C[(row0 + r) * 512 + col] = f2bf(acc[m][n][r]);
        }
}

// ------------- chunk-parallel scan, pass 1: per-chunk (A,B) summaries -------
__global__ __launch_bounds__(256)
void k_scan_p1(const unsigned short* __restrict__ q,
               const float* __restrict__ w_hh,
               const float* __restrict__ b_ih,
               float* __restrict__ Asum,
               float* __restrict__ Bsum) {
    const int g = (blockIdx.x & 63) * 256 + threadIdx.x;
    const int c = blockIdx.x >> 6;
    const float w  = w_hh[g & 511];
    const float bs = b_ih[g & 511];
    const unsigned short* p = q + (size_t)c * CLEN * S_STRIDE + g;

    float A = 0.f, Bv = 0.f;
    float s0[8], s1[8];
#pragma unroll
    for (int j = 0; j < 8; ++j) s0[j] = bf2f(p[(size_t)j * S_STRIDE]);
#pragma unroll
    for (int j = 0; j < 8; ++j) s1[j] = bf2f(p[(size_t)(8 + j) * S_STRIDE]);

    for (int j0 = 0; j0 < CLEN; j0 += 16) {
#pragma unroll
        for (int j = 0; j < 8; ++j) {
            float qv = s0[j] + bs;
            A  = fmaxf(fmaf(w, A, qv), 0.f);
            Bv = fmaf(w, Bv, qv);
        }
        if (j0 + 16 < CLEN) {
#pragma unroll
            for (int j = 0; j < 8; ++j) s0[j] = bf2f(p[(size_t)(j0 + 16 + j) * S_STRIDE]);
        }
#pragma unroll
        for (int j = 0; j < 8; ++j) {
            float qv = s1[j] + bs;
            A  = fmaxf(fmaf(w, A, qv), 0.f);
            Bv = fmaf(w, Bv, qv);
        }
        if (j0 + 24 < CLEN) {
#pragma unroll
            for (int j = 0; j < 8; ++j) s1[j] = bf2f(p[(size_t)(j0 + 24 + j) * S_STRIDE]);
        }
    }
    Asum[(size_t)c * NCHAIN + g] = A;
    Bsum[(size_t)c * NCHAIN + g] = Bv;
}

// ------------- pass 2: per-block stitch + exact replay ----------------------
template <int MODE>
__global__ __launch_bounds__(256)
void k_scan_p2(const unsigned short* __restrict__ q,
               const float* __restrict__ w_hh,
               const float* __restrict__ b_ih,
               const float* __restrict__ Asum,
               const float* __restrict__ Bsum,
               float* __restrict__ of32,
               unsigned short* __restrict__ ob16,
               float* __restrict__ hT) {
    const int g = (blockIdx.x & 63) * 256 + threadIdx.x;
    const int c = blockIdx.x >> 6;
    const float w  = w_hh[g & 511];
    const float bs = b_ih[g & 511];

    float cw = w;
#pragma unroll
    for (int i = 0; i < 7; ++i) cw *= cw;      // w^128
    float h = 0.f;
    for (int cc = 0; cc < c; ++cc)
        h = fmaxf(Asum[(size_t)cc * NCHAIN + g], fmaf(cw, h, Bsum[(size_t)cc * NCHAIN + g]));

    const size_t base = (size_t)c * CLEN * S_STRIDE + g;
    const unsigned short* p = q + base;

    float s0[8], s1[8];
#pragma unroll
    for (int j = 0; j < 8; ++j) s0[j] = bf2f(p[(size_t)j * S_STRIDE]);
#pragma unroll
    for (int j = 0; j < 8; ++j) s1[j] = bf2f(p[(size_t)(8 + j) * S_STRIDE]);

    for (int j0 = 0; j0 < CLEN; j0 += 16) {
#pragma unroll
        for (int j = 0; j < 8; ++j) {
            h = fmaxf(fmaf(w, h, s0[j] + bs), 0.f);
            const size_t idx = base + (size_t)(j0 + j) * S_STRIDE;
            if (MODE == 0) of32[idx] = h; else ob16[idx] = f2bf(h);
        }
        if (j0 + 16 < CLEN) {
#pragma unroll
            for (int j = 0; j < 8; ++j) s0[j] = bf2f(p[(size_t)(j0 + 16 + j) * S_STRIDE]);
        }
#pragma unroll
        for (int j = 0; j < 8; ++j) {
            h = fmaxf(fmaf(w, h, s1[j] + bs), 0.f);
            const size_t idx = base + (size_t)(j0 + 8 + j) * S_STRIDE;
            if (MODE == 0) of32[idx] = h; else ob16[idx] = f2bf(h);
        }
        if (j0 + 24 < CLEN) {
#pragma unroll
            for (int j = 0; j < 8; ++j) s1[j] = bf2f(p[(size_t)(j0 + 24 + j) * S_STRIDE]);
        }
    }
    if (c == NCH - 1) hT[g] = h;
}

extern "C" void kernel_launch(void* const* d_in, const int* in_sizes, int n_in,
                              void* d_out, int out_size, void* d_ws, size_t ws_size,
                              hipStream_t stream) {
    const float* x    = (const float*)d_in[0];   // (4096,32,512)
    const float* W_ih = (const float*)d_in[1];   // (2,512,512)
    const float* w_hh = (const float*)d_in[2];   // (2,512)
    const float* b_ih = (const float*)d_in[3];   // (2,512)

    // 128 KB dynamic LDS opt-in (idempotent; outside stream ops)
    hipFuncSetAttribute(reinterpret_cast<const void*>(&k_gemm8<1>),
                        hipFuncAttributeMaxDynamicSharedMemorySize, GLDS_B);
    hipFuncSetAttribute(reinterpret_cast<const void*>(&k_gemm8<0>),
                        hipFuncAttributeMaxDynamicSharedMemorySize, GLDS_B);

    // ---- workspace layout (~139 MB) ----
    unsigned short* proj2 = (unsigned short*)d_ws;                // 134 MB
    unsigned short* Wb    = proj2 + OUT_ELEMS;                    // 1 MB
    float* Asum = (float*)(Wb + 2 * 512 * 512);                   // 2 MB
    float* Bsum = Asum + (size_t)NCH * NCHAIN;                    // 2 MB

    // ---- d_out staging: proj1 (bf16) lower half, ys1 (bf16) upper half ----
    unsigned short* proj1 = (unsigned short*)d_out;
    unsigned short* ys1   = proj1 + OUT_ELEMS;
    float* out = (float*)d_out;
    float* hT  = out + OUT_ELEMS;                                 // h_n (2,32,512)

    const int sgrid = 64 * NCH;             // 2048 blocks for scan passes

    // 1. W -> bf16
    k_cvt<<<524288 / 8 / 256, 256, 0, stream>>>(W_ih, Wb);
    // 2. layer-0 GEMM (A = x f32, fused cvt) -> proj1
    k_gemm8<1><<<GNWG, 512, GLDS_B, stream>>>(x, Wb, proj1);
    // 3-4. layer-0 chunked scan -> ys1 (bf16) + hT0
    k_scan_p1<<<sgrid, 256, 0, stream>>>(proj1, w_hh, b_ih, Asum, Bsum);
    k_scan_p2<1><<<sgrid, 256, 0, stream>>>(proj1, w_hh, b_ih, Asum, Bsum,
                                            nullptr, ys1, hT);
    // 5. layer-1 GEMM (A = ys1 bf16) -> proj2 (ws)
    k_gemm8<0><<<GNWG, 512, GLDS_B, stream>>>(ys1, Wb + 512 * 512, proj2);
    // 6-7. layer-1 chunked scan -> final out (f32, overwrites proj1/ys1) + hT1
    k_scan_p1<<<sgrid, 256, 0, stream>>>(proj2, w_hh + DIM, b_ih + DIM, Asum, Bsum);
    k_scan_p2<0><<<sgrid, 256, 0, stream>>>(proj2, w_hh + DIM, b_ih + DIM, Asum, Bsum,
                                            out, nullptr, hT + NCHAIN);
}